// Round 1
// baseline (102.080 us; speedup 1.0000x reference)
//
#include <hip/hip_runtime.h>

// out[b] = clip( hardswish( dot(x[b,:], colsum(y)) ) + noise[b], -0.5, 0.5 )
// B = 8192 rows, F = 4096 features. Memory-bound: read x (128MB) + y (128MB).

namespace {

constexpr int F = 4096;
constexpr int B = 8192;

__device__ __forceinline__ void f4_add(float4& a, const float4 b) {
    a.x += b.x; a.y += b.y; a.z += b.z; a.w += b.w;
}

// Phase A: each block column-sums rows [blk*rows_per_blk, (blk+1)*rows_per_blk)
// of y into partial[blk*F .. blk*F+F). 256 threads x float4 = 1024 cols/pass,
// 4 passes cover F=4096. Fully coalesced 16B/lane loads.
__global__ __launch_bounds__(256) void colsum_partial_k(
    const float* __restrict__ y, float* __restrict__ partial, int rows_per_blk)
{
    const int blk = blockIdx.x;
    const int t   = threadIdx.x;
    const long row0 = (long)blk * rows_per_blk;

    float4 a0 = {0.f,0.f,0.f,0.f}, a1 = {0.f,0.f,0.f,0.f};
    float4 a2 = {0.f,0.f,0.f,0.f}, a3 = {0.f,0.f,0.f,0.f};

    for (int r = 0; r < rows_per_blk; ++r) {
        const float4* yrow = reinterpret_cast<const float4*>(y + (row0 + r) * F);
        f4_add(a0, yrow[0 * 256 + t]);
        f4_add(a1, yrow[1 * 256 + t]);
        f4_add(a2, yrow[2 * 256 + t]);
        f4_add(a3, yrow[3 * 256 + t]);
    }

    float4* outp = reinterpret_cast<float4*>(partial + (long)blk * F);
    outp[0 * 256 + t] = a0;
    outp[1 * 256 + t] = a1;
    outp[2 * 256 + t] = a2;
    outp[3 * 256 + t] = a3;
}

// Phase B: reduce nblk partial column-sum vectors into ysum (F floats).
// Grid = F/1024 blocks of 256 threads, each thread owns one float4 column slot.
__global__ __launch_bounds__(256) void colsum_final_k(
    const float* __restrict__ partial, float* __restrict__ ysum, int nblk)
{
    const int idx = blockIdx.x * 256 + threadIdx.x;   // float4 index, 0..F/4-1
    float4 acc = {0.f,0.f,0.f,0.f};
    for (int p = 0; p < nblk; ++p) {
        f4_add(acc, reinterpret_cast<const float4*>(partial + (long)p * F)[idx]);
    }
    reinterpret_cast<float4*>(ysum)[idx] = acc;
}

// Phase C: one block per row. dot(x[b,:], ysum) -> hardswish -> +noise -> clip.
__global__ __launch_bounds__(256) void rowdot_k(
    const float* __restrict__ x, const float* __restrict__ ysum,
    const float* __restrict__ noise, float* __restrict__ out)
{
    const int b = blockIdx.x;
    const int t = threadIdx.x;

    const float4* xrow = reinterpret_cast<const float4*>(x + (long)b * F);
    const float4* ys   = reinterpret_cast<const float4*>(ysum);

    float p = 0.f;
#pragma unroll
    for (int g = 0; g < 4; ++g) {
        float4 xv = xrow[g * 256 + t];
        float4 yv = ys[g * 256 + t];
        p += xv.x * yv.x + xv.y * yv.y + xv.z * yv.z + xv.w * yv.w;
    }

    // wave-64 butterfly-free down-reduce
#pragma unroll
    for (int off = 32; off > 0; off >>= 1) p += __shfl_down(p, off);

    __shared__ float wsum[4];
    if ((t & 63) == 0) wsum[t >> 6] = p;
    __syncthreads();

    if (t == 0) {
        float s = wsum[0] + wsum[1] + wsum[2] + wsum[3];
        // hardswish: s * clip(s+3, 0, 6) / 6
        float h = s * fminf(fmaxf(s + 3.0f, 0.0f), 6.0f) * (1.0f / 6.0f);
        // logsumexp over singleton axis == identity; add noise; hardtanh(-0.5,0.5)
        float r = h + noise[b];
        out[b] = fminf(fmaxf(r, -0.5f), 0.5f);
    }
}

} // namespace

extern "C" void kernel_launch(void* const* d_in, const int* in_sizes, int n_in,
                              void* d_out, int out_size, void* d_ws, size_t ws_size,
                              hipStream_t stream)
{
    const float* x     = (const float*)d_in[0];   // (B, F)
    const float* y     = (const float*)d_in[1];   // (B, F)
    const float* noise = (const float*)d_in[2];   // (B, 1)
    float*       out   = (float*)d_out;           // (B, 1) fp32

    // Workspace layout: [nb * F floats partials][F floats ysum]
    int nb = 64;
    while (nb > 1 && (size_t)(nb + 1) * F * sizeof(float) > ws_size) nb >>= 1;
    float* partial = (float*)d_ws;
    float* ysum    = partial + (size_t)nb * F;
    const int rows_per_blk = B / nb;

    colsum_partial_k<<<nb,        256, 0, stream>>>(y, partial, rows_per_blk);
    colsum_final_k  <<<F / 1024,  256, 0, stream>>>(partial, ysum, nb);
    rowdot_k        <<<B,         256, 0, stream>>>(x, ysum, noise, out);
}